// Round 15
// baseline (179.024 us; speedup 1.0000x reference)
//
#include <hip/hip_runtime.h>
#include <hip/hip_bf16.h>
#include <math.h>

#define N_NODES 50000
#define NEG_SLOPE 0.2f
#define EPS_DEN 1e-16f

#define NBUCK 196          // ceil(N_NODES / 256)
#define NBLK  512          // edge-pass blocks

typedef float f4v __attribute__((ext_vector_type(4)));

// ---------------- prep: Wa[i][h] = sum_o W[i,h,o]*a[h,o] ----------------
__global__ void __launch_bounds__(256) prep_k(
    const float* __restrict__ W, const float* __restrict__ aS,
    const float* __restrict__ aD, float* __restrict__ WaSD)
{
    int tid = threadIdx.x;
    int h = tid >> 6, i = tid & 63;
    const float* wrow = W + (size_t)i * 256 + h * 64;
    const float* as = aS + h * 64;
    const float* ad = aD + h * 64;
    float ws = 0.f, wd = 0.f;
    #pragma unroll 8
    for (int o = 0; o < 64; ++o) {
        float w = wrow[o];
        ws = fmaf(w, as[o], ws);
        wd = fmaf(w, ad[o], wd);
    }
    WaSD[i * 8 + h]     = ws;
    WaSD[i * 8 + 4 + h] = wd;
}

// ---------------- alpha: asrc/adst[n,h] = x[n,:] . Wa[:,h] ----------------
__global__ void __launch_bounds__(256) alpha_k(
    const float* __restrict__ x, const float* __restrict__ WaSD,
    float* __restrict__ asrc, float* __restrict__ adst, int N)
{
    __shared__ float Wl[512];
    int tid = threadIdx.x;
    Wl[tid]       = WaSD[tid];
    Wl[tid + 256] = WaSD[tid + 256];
    __syncthreads();

    int node = blockIdx.x * 64 + (tid >> 2);
    int q = tid & 3;
    if (node >= N) return;

    float pS[4] = {0.f, 0.f, 0.f, 0.f};
    float pD[4] = {0.f, 0.f, 0.f, 0.f};
    const float* xp = x + (size_t)node * 64 + q * 16;
    #pragma unroll
    for (int j = 0; j < 4; ++j) {
        float4 xv = *(const float4*)(xp + j * 4);
        float xr[4] = {xv.x, xv.y, xv.z, xv.w};
        #pragma unroll
        for (int u = 0; u < 4; ++u) {
            int i = q * 16 + j * 4 + u;
            float4 wS = *(const float4*)(Wl + i * 8);
            float4 wD = *(const float4*)(Wl + i * 8 + 4);
            pS[0] = fmaf(xr[u], wS.x, pS[0]); pS[1] = fmaf(xr[u], wS.y, pS[1]);
            pS[2] = fmaf(xr[u], wS.z, pS[2]); pS[3] = fmaf(xr[u], wS.w, pS[3]);
            pD[0] = fmaf(xr[u], wD.x, pD[0]); pD[1] = fmaf(xr[u], wD.y, pD[1]);
            pD[2] = fmaf(xr[u], wD.z, pD[2]); pD[3] = fmaf(xr[u], wD.w, pD[3]);
        }
    }
    #pragma unroll
    for (int off = 1; off <= 2; off <<= 1) {
        #pragma unroll
        for (int h = 0; h < 4; ++h) {
            pS[h] += __shfl_xor(pS[h], off);
            pD[h] += __shfl_xor(pD[h], off);
        }
    }
    if (q == 0) {
        *(float4*)(asrc + 4 * (size_t)node) = make_float4(pS[0], pS[1], pS[2], pS[3]);
        *(float4*)(adst + 4 * (size_t)node) = make_float4(pD[0], pD[1], pD[2], pD[3]);
    }
}

// ---------------- CSR build (atomic-light bucketed counting sort) ----------------
__global__ void __launch_bounds__(256) hist_bucket_k(
    const int* __restrict__ ei, int* __restrict__ bh, int E)
{
    __shared__ int lh[NBUCK];
    int tid = threadIdx.x;
    for (int b = tid; b < NBUCK; b += 256) lh[b] = 0;
    __syncthreads();

    const int ch = (E + NBLK - 1) / NBLK;
    const int e0 = blockIdx.x * ch;
    const int e1 = min(e0 + ch, E);
    for (int e = e0 + tid; e < e1; e += 256)
        atomicAdd(&lh[ei[E + e] >> 8], 1);
    __syncthreads();
    for (int b = tid; b < NBUCK; b += 256)
        bh[(size_t)b * NBLK + blockIdx.x] = lh[b];
}

__global__ void __launch_bounds__(64) bscan_k(
    const int* __restrict__ bh, int* __restrict__ boffL, int* __restrict__ btot)
{
    const int b = blockIdx.x;
    const int lane = threadIdx.x;
    int v[8];
    int base = b * NBLK;
    #pragma unroll
    for (int u = 0; u < 8; ++u) v[u] = bh[base + lane * 8 + u];
    int t = 0;
    #pragma unroll
    for (int u = 0; u < 8; ++u) t += v[u];
    int run = t;
    #pragma unroll
    for (int off = 1; off < 64; off <<= 1) {
        int u = __shfl_up(run, off);
        if (lane >= off) run += u;
    }
    int lane_base = run - t;
    #pragma unroll
    for (int u = 0; u < 8; ++u) {
        boffL[base + lane * 8 + u] = lane_base;
        lane_base += v[u];
    }
    if (lane == 63) btot[b] = run;
}

__global__ void __launch_bounds__(256) btot_k(
    const int* __restrict__ btot, int* __restrict__ bbase,
    int* __restrict__ row, int N, int E)
{
    __shared__ int sd[256];
    int tid = threadIdx.x;
    int v = (tid < NBUCK) ? btot[tid] : 0;
    sd[tid] = v;
    __syncthreads();
    for (int off = 1; off < 256; off <<= 1) {
        int t = (tid >= off) ? sd[tid - off] : 0;
        __syncthreads();
        sd[tid] += t;
        __syncthreads();
    }
    if (tid < NBUCK) bbase[tid] = sd[tid] - v;
    if (tid == 0) { bbase[NBUCK] = E; row[N] = E; }
}

__global__ void __launch_bounds__(256) bplace_k(
    const int* __restrict__ ei, const int* __restrict__ bbase,
    const int* __restrict__ boffL, unsigned int* __restrict__ stage, int E)
{
    __shared__ int cur[NBUCK];
    int tid = threadIdx.x;
    for (int b = tid; b < NBUCK; b += 256)
        cur[b] = bbase[b] + boffL[(size_t)b * NBLK + blockIdx.x];
    __syncthreads();

    const int ch = (E + NBLK - 1) / NBLK;
    const int e0 = blockIdx.x * ch;
    const int e1 = min(e0 + ch, E);
    for (int e = e0 + tid; e < e1; e += 256) {
        int s = ei[e];
        int d = ei[E + e];
        int pos = atomicAdd(&cur[d >> 8], 1);
        stage[pos] = (unsigned int)s | ((unsigned int)(d & 255) << 16);
    }
}

__global__ void __launch_bounds__(256) bscatter_k(
    const unsigned int* __restrict__ stage, const int* __restrict__ bbase,
    int* __restrict__ row, int* __restrict__ psrc, int N)
{
    __shared__ int cnt[256];
    __shared__ int sd[256];
    __shared__ int cur[256];
    const int b = blockIdx.x;
    const int tid = threadIdx.x;
    const int nb0 = b << 8;
    const int es = bbase[b], ee = bbase[b + 1];

    cnt[tid] = 0;
    __syncthreads();
    for (int idx = es + tid; idx < ee; idx += 256)
        atomicAdd(&cnt[(stage[idx] >> 16) & 255], 1);
    __syncthreads();

    int v = cnt[tid];
    sd[tid] = v;
    __syncthreads();
    for (int off = 1; off < 256; off <<= 1) {
        int t = (tid >= off) ? sd[tid - off] : 0;
        __syncthreads();
        sd[tid] += t;
        __syncthreads();
    }
    int r = es + sd[tid] - v;
    int node = nb0 + tid;
    if (node < N) row[node] = r;
    cur[tid] = r;
    __syncthreads();

    for (int idx = es + tid; idx < ee; idx += 256) {
        unsigned int w = stage[idx];
        int pos = atomicAdd(&cur[(w >> 16) & 255], 1);
        psrc[pos] = w & 0xFFFF;
    }
}

// ---------------- FUSED aggregate + (z.W) + bias + relu ----------------
// Block = 256 threads = 16 nodes x 16 lanes (phase 1).
// LDS EXACTLY 20480 B -> 8 blocks/CU: pL 1024 f4 (16 KB) + sI 1024 int (4 KB),
// rotation swizzle idx = slot*64 + ((j+slot)&63) replaces padding (same 2-way
// write aliasing, conflict-free broadcast reads). Time-multiplexed:
// [pL|sI] -> zT[k*18+n] -> red.
#define MAXDEG4 64
__global__ void __launch_bounds__(256, 8) aggzw_k(
    const float* __restrict__ x, const float* __restrict__ asrc,
    const float* __restrict__ adst, const int* __restrict__ row,
    const int* __restrict__ psrc, const float* __restrict__ W,
    const float* __restrict__ bias, float* __restrict__ out, int N)
{
    __shared__ float smem[5120];                // 20480 B exactly
    float4* pL = (float4*)smem;                 // phase 1: 1024 float4
    int*    sI = (int*)(smem + 4096);           // phase 1: 1024 int
    float*  zt = smem;                          // zT[k][n]: k*18 + n (4608 f)
    float*  red = smem;                         // reduction alias (4096 f)

    const int tid  = threadIdx.x;
    const int li   = tid & 15;
    const int slot = tid >> 4;                  // 0..15 (node within block)
    const int n = blockIdx.x * 16 + slot;
    const bool active = n < N;

    auto IDX = [&](int j) { return slot * 64 + ((j + slot) & 63); };

    int rs = 0, deg = 0;
    float4 ad = make_float4(0.f, 0.f, 0.f, 0.f);
    if (active) {
        rs  = row[n];
        deg = row[n + 1] - rs;
        ad  = *(const float4*)(adst + 4 * (size_t)n);
    }

    float m0 = -INFINITY, m1 = -INFINITY, m2 = -INFINITY, m3 = -INFINITY;
    float s0 = 0.f, s1 = 0.f, s2 = 0.f, s3 = 0.f;
    float4 a0 = make_float4(0.f,0.f,0.f,0.f), a1 = a0, a2 = a0, a3 = a0;

    auto ACC = [&](const float4& p, const float4& xv) {
        a0.x = fmaf(p.x, xv.x, a0.x); a0.y = fmaf(p.x, xv.y, a0.y);
        a0.z = fmaf(p.x, xv.z, a0.z); a0.w = fmaf(p.x, xv.w, a0.w);
        a1.x = fmaf(p.y, xv.x, a1.x); a1.y = fmaf(p.y, xv.y, a1.y);
        a1.z = fmaf(p.y, xv.z, a1.z); a1.w = fmaf(p.y, xv.w, a1.w);
        a2.x = fmaf(p.z, xv.x, a2.x); a2.y = fmaf(p.z, xv.y, a2.y);
        a2.z = fmaf(p.z, xv.z, a2.z); a2.w = fmaf(p.z, xv.w, a2.w);
        a3.x = fmaf(p.w, xv.x, a3.x); a3.y = fmaf(p.w, xv.y, a3.y);
        a3.z = fmaf(p.w, xv.z, a3.z); a3.w = fmaf(p.w, xv.w, a3.w);
    };

    if (deg <= MAXDEG4) {
        for (int j = li; j < deg; j += 16) {
            int s = psrc[rs + j];
            int ix = IDX(j);
            sI[ix] = s;
            float4 a = *(const float4*)(asrc + 4 * (size_t)s);
            float e0 = a.x + ad.x; e0 = e0 > 0.f ? e0 : NEG_SLOPE * e0;
            float e1 = a.y + ad.y; e1 = e1 > 0.f ? e1 : NEG_SLOPE * e1;
            float e2 = a.z + ad.z; e2 = e2 > 0.f ? e2 : NEG_SLOPE * e2;
            float e3 = a.w + ad.w; e3 = e3 > 0.f ? e3 : NEG_SLOPE * e3;
            pL[ix] = make_float4(e0, e1, e2, e3);
            m0 = fmaxf(m0, e0); m1 = fmaxf(m1, e1);
            m2 = fmaxf(m2, e2); m3 = fmaxf(m3, e3);
        }
        #pragma unroll
        for (int off = 1; off < 16; off <<= 1) {
            m0 = fmaxf(m0, __shfl_xor(m0, off));
            m1 = fmaxf(m1, __shfl_xor(m1, off));
            m2 = fmaxf(m2, __shfl_xor(m2, off));
            m3 = fmaxf(m3, __shfl_xor(m3, off));
        }
        for (int j = li; j < deg; j += 16) {
            int ix = IDX(j);
            float4 e = pL[ix];
            float4 p = make_float4(__expf(e.x - m0), __expf(e.y - m1),
                                   __expf(e.z - m2), __expf(e.w - m3));
            pL[ix] = p;
            s0 += p.x; s1 += p.y; s2 += p.z; s3 += p.w;
        }
        #pragma unroll
        for (int off = 1; off < 16; off <<= 1) {
            s0 += __shfl_xor(s0, off);
            s1 += __shfl_xor(s1, off);
            s2 += __shfl_xor(s2, off);
            s3 += __shfl_xor(s3, off);
        }
        // pass 3: simple loop (compiler pipelines); src index from LDS
        #pragma unroll 2
        for (int j = 0; j < deg; ++j) {
            int ix = IDX(j);
            int s = sI[ix];
            float4 p = pL[ix];
            float4 xv = *(const float4*)(x + (size_t)s * 64 + li * 4);
            ACC(p, xv);
        }
    } else {
        // fallback deg > 64: recompute logits, no LDS
        for (int j = li; j < deg; j += 16) {
            int s = psrc[rs + j];
            float4 a = *(const float4*)(asrc + 4 * (size_t)s);
            float e0 = a.x + ad.x; e0 = e0 > 0.f ? e0 : NEG_SLOPE * e0;
            float e1 = a.y + ad.y; e1 = e1 > 0.f ? e1 : NEG_SLOPE * e1;
            float e2 = a.z + ad.z; e2 = e2 > 0.f ? e2 : NEG_SLOPE * e2;
            float e3 = a.w + ad.w; e3 = e3 > 0.f ? e3 : NEG_SLOPE * e3;
            m0 = fmaxf(m0, e0); m1 = fmaxf(m1, e1);
            m2 = fmaxf(m2, e2); m3 = fmaxf(m3, e3);
        }
        #pragma unroll
        for (int off = 1; off < 16; off <<= 1) {
            m0 = fmaxf(m0, __shfl_xor(m0, off));
            m1 = fmaxf(m1, __shfl_xor(m1, off));
            m2 = fmaxf(m2, __shfl_xor(m2, off));
            m3 = fmaxf(m3, __shfl_xor(m3, off));
        }
        for (int j = li; j < deg; j += 16) {
            int s = psrc[rs + j];
            float4 a = *(const float4*)(asrc + 4 * (size_t)s);
            float e0 = a.x + ad.x; e0 = e0 > 0.f ? e0 : NEG_SLOPE * e0;
            float e1 = a.y + ad.y; e1 = e1 > 0.f ? e1 : NEG_SLOPE * e1;
            float e2 = a.z + ad.z; e2 = e2 > 0.f ? e2 : NEG_SLOPE * e2;
            float e3 = a.w + ad.w; e3 = e3 > 0.f ? e3 : NEG_SLOPE * e3;
            s0 += __expf(e0 - m0); s1 += __expf(e1 - m1);
            s2 += __expf(e2 - m2); s3 += __expf(e3 - m3);
        }
        #pragma unroll
        for (int off = 1; off < 16; off <<= 1) {
            s0 += __shfl_xor(s0, off);
            s1 += __shfl_xor(s1, off);
            s2 += __shfl_xor(s2, off);
            s3 += __shfl_xor(s3, off);
        }
        for (int j = 0; j < deg; ++j) {
            int s = psrc[rs + j];
            float4 a = *(const float4*)(asrc + 4 * (size_t)s);
            float e0 = a.x + ad.x; e0 = e0 > 0.f ? e0 : NEG_SLOPE * e0;
            float e1 = a.y + ad.y; e1 = e1 > 0.f ? e1 : NEG_SLOPE * e1;
            float e2 = a.z + ad.z; e2 = e2 > 0.f ? e2 : NEG_SLOPE * e2;
            float e3 = a.w + ad.w; e3 = e3 > 0.f ? e3 : NEG_SLOPE * e3;
            float p0 = __expf(e0 - m0), p1 = __expf(e1 - m1);
            float p2 = __expf(e2 - m2), p3 = __expf(e3 - m3);
            float4 xv = *(const float4*)(x + (size_t)s * 64 + li * 4);
            ACC(make_float4(p0, p1, p2, p3), xv);
        }
    }

    // all pL/sI reads done everywhere, then write zT over the same region
    __syncthreads();
    if (active) {
        float i0 = 0.25f / (s0 + EPS_DEN), i1 = 0.25f / (s1 + EPS_DEN);
        float i2 = 0.25f / (s2 + EPS_DEN), i3 = 0.25f / (s3 + EPS_DEN);
        float* zb = zt + (li * 4) * 18 + slot;
        zb[0]  = a0.x * i0; zb[18] = a0.y * i0; zb[36] = a0.z * i0; zb[54] = a0.w * i0;
        zb += 64 * 18;
        zb[0]  = a1.x * i1; zb[18] = a1.y * i1; zb[36] = a1.z * i1; zb[54] = a1.w * i1;
        zb += 64 * 18;
        zb[0]  = a2.x * i2; zb[18] = a2.y * i2; zb[36] = a2.z * i2; zb[54] = a2.w * i2;
        zb += 64 * 18;
        zb[0]  = a3.x * i3; zb[18] = a3.y * i3; zb[36] = a3.z * i3; zb[54] = a3.w * i3;
    }
    __syncthreads();

    // ---------------- phase 2: out[16x64] = zT^T . W', W from global ----------------
    const int ks = tid >> 6;          // wave id = k subset
    const int ng = (tid >> 4) & 3;    // node group (4 nodes)
    const int og = tid & 15;          // col group (4 cols)
    float acc[4][4];
    #pragma unroll
    for (int i = 0; i < 4; ++i)
        #pragma unroll
        for (int j = 0; j < 4; ++j) acc[i][j] = 0.f;

    const float* wp = W + (size_t)ks * 64 + og * 4;   // W[kk*256 + ks*64 + og*4]
    #pragma unroll 8
    for (int kk = 0; kk < 64; ++kk) {
        int kg = ks * 64 + kk;
        float2 zA = *(const float2*)(zt + kg * 18 + ng * 4);
        float2 zB = *(const float2*)(zt + kg * 18 + ng * 4 + 2);
        float4 wv = *(const float4*)(wp + (size_t)kk * 256);
        float zr[4] = {zA.x, zA.y, zB.x, zB.y};
        float wc4[4] = {wv.x, wv.y, wv.z, wv.w};
        #pragma unroll
        for (int i = 0; i < 4; ++i)
            #pragma unroll
            for (int j = 0; j < 4; ++j)
                acc[i][j] = fmaf(zr[i], wc4[j], acc[i][j]);
    }

    // cross-wave reduction of the 4 k-subsets (red aliases zT)
    __syncthreads();
    #pragma unroll
    for (int i = 0; i < 4; ++i)
        *(float4*)(red + ((ks * 16 + ng * 4 + i) * 16 + og) * 4) =
            make_float4(acc[i][0], acc[i][1], acc[i][2], acc[i][3]);
    __syncthreads();

    {
        int nl = tid >> 4;
        int o  = tid & 15;
        const float4* r4 = (const float4*)red;
        float4 p0 = r4[      nl * 16 + o];
        float4 p1 = r4[256 + nl * 16 + o];
        float4 p2 = r4[512 + nl * 16 + o];
        float4 p3 = r4[768 + nl * 16 + o];
        int gn = blockIdx.x * 16 + nl;
        if (gn < N) {
            float4 b4 = *(const float4*)(bias + o * 4);
            float4 ov;
            ov.x = fmaxf(p0.x + p1.x + p2.x + p3.x + b4.x, 0.f);
            ov.y = fmaxf(p0.y + p1.y + p2.y + p3.y + b4.y, 0.f);
            ov.z = fmaxf(p0.z + p1.z + p2.z + p3.z + b4.z, 0.f);
            ov.w = fmaxf(p0.w + p1.w + p2.w + p3.w + b4.w, 0.f);
            *(float4*)(out + (size_t)gn * 64 + o * 4) = ov;
        }
    }
}

// ---------------- launch ----------------
extern "C" void kernel_launch(void* const* d_in, const int* in_sizes, int n_in,
                              void* d_out, int out_size, void* d_ws, size_t ws_size,
                              hipStream_t stream)
{
    const float* x   = (const float*)d_in[0];
    const int*   ei  = (const int*)d_in[1];
    const float* W1  = (const float*)d_in[4];
    const float* as1 = (const float*)d_in[5];
    const float* ad1 = (const float*)d_in[6];
    const float* b1  = (const float*)d_in[7];
    const float* W2  = (const float*)d_in[8];
    const float* as2 = (const float*)d_in[9];
    const float* ad2 = (const float*)d_in[10];
    const float* b2  = (const float*)d_in[11];

    const int E = in_sizes[1] / 2;
    const int N = N_NODES;

    char* ws = (char*)d_ws;
    size_t off = 0;
    auto alloc = [&](size_t bytes) -> void* {
        void* p = ws + off;
        off = (off + bytes + 255) & ~(size_t)255;
        return p;
    };
    float*        x1    = (float*)alloc((size_t)N * 64 * 4);
    float*        asrc  = (float*)alloc((size_t)N * 4 * 4);
    float*        adst  = (float*)alloc((size_t)N * 4 * 4);
    float*        WaSD  = (float*)alloc(64 * 8 * 4);
    int*          row   = (int*)alloc((size_t)(N + 1) * 4);
    int*          psrc  = (int*)alloc((size_t)E * 4);
    int*          bh    = (int*)alloc((size_t)NBUCK * NBLK * 4);
    int*          boffL = (int*)alloc((size_t)NBUCK * NBLK * 4);
    int*          btot  = (int*)alloc((NBUCK + 1) * 4);
    int*          bbase = (int*)alloc((NBUCK + 1) * 4);
    unsigned int* stage = (unsigned int*)alloc((size_t)E * 4);

    // CSR (shared by both layers)
    hist_bucket_k<<<NBLK, 256, 0, stream>>>(ei, bh, E);
    bscan_k<<<NBUCK, 64, 0, stream>>>(bh, boffL, btot);
    btot_k<<<1, 256, 0, stream>>>(btot, bbase, row, N, E);
    bplace_k<<<NBLK, 256, 0, stream>>>(ei, bbase, boffL, stage, E);
    bscatter_k<<<NBUCK, 256, 0, stream>>>(stage, bbase, row, psrc, N);

    const int nblk64 = (N + 63) / 64;
    const int nblk16 = (N + 15) / 16;

    // layer 1
    prep_k<<<1, 256, 0, stream>>>(W1, as1, ad1, WaSD);
    alpha_k<<<nblk64, 256, 0, stream>>>(x, WaSD, asrc, adst, N);
    aggzw_k<<<nblk16, 256, 0, stream>>>(x, asrc, adst, row, psrc, W1, b1, x1, N);

    // layer 2
    prep_k<<<1, 256, 0, stream>>>(W2, as2, ad2, WaSD);
    alpha_k<<<nblk64, 256, 0, stream>>>(x1, WaSD, asrc, adst, N);
    aggzw_k<<<nblk16, 256, 0, stream>>>(x1, asrc, adst, row, psrc, W2, b2, (float*)d_out, N);
}

// Round 16
// 162.219 us; speedup vs baseline: 1.1036x; 1.1036x over previous
//
#include <hip/hip_runtime.h>
#include <hip/hip_bf16.h>
#include <math.h>

#define N_NODES 50000
#define NEG_SLOPE 0.2f
#define EPS_DEN 1e-16f

#define NBUCK 196          // ceil(N_NODES / 256)
#define NBLK  512          // edge-pass blocks

typedef float f4v __attribute__((ext_vector_type(4)));

// ---------------- prep: Wa[i][h] = sum_o W[i,h,o]*a[h,o] ----------------
__global__ void __launch_bounds__(256) prep_k(
    const float* __restrict__ W, const float* __restrict__ aS,
    const float* __restrict__ aD, float* __restrict__ WaSD)
{
    int tid = threadIdx.x;
    int h = tid >> 6, i = tid & 63;
    const float* wrow = W + (size_t)i * 256 + h * 64;
    const float* as = aS + h * 64;
    const float* ad = aD + h * 64;
    float ws = 0.f, wd = 0.f;
    #pragma unroll 8
    for (int o = 0; o < 64; ++o) {
        float w = wrow[o];
        ws = fmaf(w, as[o], ws);
        wd = fmaf(w, ad[o], wd);
    }
    WaSD[i * 8 + h]     = ws;
    WaSD[i * 8 + 4 + h] = wd;
}

// ---------------- alpha: asrc/adst[n,h] = x[n,:] . Wa[:,h] ----------------
__global__ void __launch_bounds__(256) alpha_k(
    const float* __restrict__ x, const float* __restrict__ WaSD,
    float* __restrict__ asrc, float* __restrict__ adst, int N)
{
    __shared__ float Wl[512];
    int tid = threadIdx.x;
    Wl[tid]       = WaSD[tid];
    Wl[tid + 256] = WaSD[tid + 256];
    __syncthreads();

    int node = blockIdx.x * 64 + (tid >> 2);
    int q = tid & 3;
    if (node >= N) return;

    float pS[4] = {0.f, 0.f, 0.f, 0.f};
    float pD[4] = {0.f, 0.f, 0.f, 0.f};
    const float* xp = x + (size_t)node * 64 + q * 16;
    #pragma unroll
    for (int j = 0; j < 4; ++j) {
        float4 xv = *(const float4*)(xp + j * 4);
        float xr[4] = {xv.x, xv.y, xv.z, xv.w};
        #pragma unroll
        for (int u = 0; u < 4; ++u) {
            int i = q * 16 + j * 4 + u;
            float4 wS = *(const float4*)(Wl + i * 8);
            float4 wD = *(const float4*)(Wl + i * 8 + 4);
            pS[0] = fmaf(xr[u], wS.x, pS[0]); pS[1] = fmaf(xr[u], wS.y, pS[1]);
            pS[2] = fmaf(xr[u], wS.z, pS[2]); pS[3] = fmaf(xr[u], wS.w, pS[3]);
            pD[0] = fmaf(xr[u], wD.x, pD[0]); pD[1] = fmaf(xr[u], wD.y, pD[1]);
            pD[2] = fmaf(xr[u], wD.z, pD[2]); pD[3] = fmaf(xr[u], wD.w, pD[3]);
        }
    }
    #pragma unroll
    for (int off = 1; off <= 2; off <<= 1) {
        #pragma unroll
        for (int h = 0; h < 4; ++h) {
            pS[h] += __shfl_xor(pS[h], off);
            pD[h] += __shfl_xor(pD[h], off);
        }
    }
    if (q == 0) {
        *(float4*)(asrc + 4 * (size_t)node) = make_float4(pS[0], pS[1], pS[2], pS[3]);
        *(float4*)(adst + 4 * (size_t)node) = make_float4(pD[0], pD[1], pD[2], pD[3]);
    }
}

// ---------------- CSR build (atomic-light bucketed counting sort) ----------------
__global__ void __launch_bounds__(256) hist_bucket_k(
    const int* __restrict__ ei, int* __restrict__ bh, int E)
{
    __shared__ int lh[NBUCK];
    int tid = threadIdx.x;
    for (int b = tid; b < NBUCK; b += 256) lh[b] = 0;
    __syncthreads();

    const int ch = (E + NBLK - 1) / NBLK;
    const int e0 = blockIdx.x * ch;
    const int e1 = min(e0 + ch, E);
    for (int e = e0 + tid; e < e1; e += 256)
        atomicAdd(&lh[ei[E + e] >> 8], 1);
    __syncthreads();
    for (int b = tid; b < NBUCK; b += 256)
        bh[(size_t)b * NBLK + blockIdx.x] = lh[b];
}

__global__ void __launch_bounds__(64) bscan_k(
    const int* __restrict__ bh, int* __restrict__ boffL, int* __restrict__ btot)
{
    const int b = blockIdx.x;
    const int lane = threadIdx.x;
    int v[8];
    int base = b * NBLK;
    #pragma unroll
    for (int u = 0; u < 8; ++u) v[u] = bh[base + lane * 8 + u];
    int t = 0;
    #pragma unroll
    for (int u = 0; u < 8; ++u) t += v[u];
    int run = t;
    #pragma unroll
    for (int off = 1; off < 64; off <<= 1) {
        int u = __shfl_up(run, off);
        if (lane >= off) run += u;
    }
    int lane_base = run - t;
    #pragma unroll
    for (int u = 0; u < 8; ++u) {
        boffL[base + lane * 8 + u] = lane_base;
        lane_base += v[u];
    }
    if (lane == 63) btot[b] = run;
}

__global__ void __launch_bounds__(256) btot_k(
    const int* __restrict__ btot, int* __restrict__ bbase,
    int* __restrict__ row, int N, int E)
{
    __shared__ int sd[256];
    int tid = threadIdx.x;
    int v = (tid < NBUCK) ? btot[tid] : 0;
    sd[tid] = v;
    __syncthreads();
    for (int off = 1; off < 256; off <<= 1) {
        int t = (tid >= off) ? sd[tid - off] : 0;
        __syncthreads();
        sd[tid] += t;
        __syncthreads();
    }
    if (tid < NBUCK) bbase[tid] = sd[tid] - v;
    if (tid == 0) { bbase[NBUCK] = E; row[N] = E; }
}

__global__ void __launch_bounds__(256) bplace_k(
    const int* __restrict__ ei, const int* __restrict__ bbase,
    const int* __restrict__ boffL, unsigned int* __restrict__ stage, int E)
{
    __shared__ int cur[NBUCK];
    int tid = threadIdx.x;
    for (int b = tid; b < NBUCK; b += 256)
        cur[b] = bbase[b] + boffL[(size_t)b * NBLK + blockIdx.x];
    __syncthreads();

    const int ch = (E + NBLK - 1) / NBLK;
    const int e0 = blockIdx.x * ch;
    const int e1 = min(e0 + ch, E);
    for (int e = e0 + tid; e < e1; e += 256) {
        int s = ei[e];
        int d = ei[E + e];
        int pos = atomicAdd(&cur[d >> 8], 1);
        stage[pos] = (unsigned int)s | ((unsigned int)(d & 255) << 16);
    }
}

__global__ void __launch_bounds__(256) bscatter_k(
    const unsigned int* __restrict__ stage, const int* __restrict__ bbase,
    int* __restrict__ row, int* __restrict__ psrc, int N)
{
    __shared__ int cnt[256];
    __shared__ int sd[256];
    __shared__ int cur[256];
    const int b = blockIdx.x;
    const int tid = threadIdx.x;
    const int nb0 = b << 8;
    const int es = bbase[b], ee = bbase[b + 1];

    cnt[tid] = 0;
    __syncthreads();
    for (int idx = es + tid; idx < ee; idx += 256)
        atomicAdd(&cnt[(stage[idx] >> 16) & 255], 1);
    __syncthreads();

    int v = cnt[tid];
    sd[tid] = v;
    __syncthreads();
    for (int off = 1; off < 256; off <<= 1) {
        int t = (tid >= off) ? sd[tid - off] : 0;
        __syncthreads();
        sd[tid] += t;
        __syncthreads();
    }
    int r = es + sd[tid] - v;
    int node = nb0 + tid;
    if (node < N) row[node] = r;
    cur[tid] = r;
    __syncthreads();

    for (int idx = es + tid; idx < ee; idx += 256) {
        unsigned int w = stage[idx];
        int pos = atomicAdd(&cur[(w >> 16) & 255], 1);
        psrc[pos] = w & 0xFFFF;
    }
}

// ---------------- FUSED aggregate + (z.W) + bias + relu ----------------
// Block = 256 threads = 16 nodes x 16 lanes (phase 1).
// LDS 20.8 KB time-multiplexed: [pL | sI] -> zT[k*18+n] -> red.
// R14-proven config: pad-65 layout, sI in LDS, stride-18 zT, bound(256,8).
#define MAXDEG4 64
__global__ void __launch_bounds__(256, 8) aggzw_k(
    const float* __restrict__ x, const float* __restrict__ asrc,
    const float* __restrict__ adst, const int* __restrict__ row,
    const int* __restrict__ psrc, const float* __restrict__ W,
    const float* __restrict__ bias, float* __restrict__ out, int N)
{
    __shared__ float smem[5200];                // 20.8 KB
    float4* pL = (float4*)smem;                 // phase 1: [slot*65 + j] (4160 f)
    int*    sI = (int*)(smem + 4160);           // phase 1: [slot*65 + j] (1040 i)
    float*  zt = smem;                          // zT[k][n]: k*18 + n (4608 f)
    float*  red = smem;                         // reduction alias (4096 f)

    const int tid  = threadIdx.x;
    const int li   = tid & 15;
    const int slot = tid >> 4;                  // 0..15 (node within block)
    const int n = blockIdx.x * 16 + slot;
    const bool active = n < N;

    int rs = 0, deg = 0;
    float4 ad = make_float4(0.f, 0.f, 0.f, 0.f);
    if (active) {
        rs  = row[n];
        deg = row[n + 1] - rs;
        ad  = *(const float4*)(adst + 4 * (size_t)n);
    }

    float m0 = -INFINITY, m1 = -INFINITY, m2 = -INFINITY, m3 = -INFINITY;
    float s0 = 0.f, s1 = 0.f, s2 = 0.f, s3 = 0.f;
    float4 a0 = make_float4(0.f,0.f,0.f,0.f), a1 = a0, a2 = a0, a3 = a0;

    auto ACC = [&](const float4& p, const float4& xv) {
        a0.x = fmaf(p.x, xv.x, a0.x); a0.y = fmaf(p.x, xv.y, a0.y);
        a0.z = fmaf(p.x, xv.z, a0.z); a0.w = fmaf(p.x, xv.w, a0.w);
        a1.x = fmaf(p.y, xv.x, a1.x); a1.y = fmaf(p.y, xv.y, a1.y);
        a1.z = fmaf(p.y, xv.z, a1.z); a1.w = fmaf(p.y, xv.w, a1.w);
        a2.x = fmaf(p.z, xv.x, a2.x); a2.y = fmaf(p.z, xv.y, a2.y);
        a2.z = fmaf(p.z, xv.z, a2.z); a2.w = fmaf(p.z, xv.w, a2.w);
        a3.x = fmaf(p.w, xv.x, a3.x); a3.y = fmaf(p.w, xv.y, a3.y);
        a3.z = fmaf(p.w, xv.z, a3.z); a3.w = fmaf(p.w, xv.w, a3.w);
    };

    if (deg <= MAXDEG4) {
        for (int j = li; j < deg; j += 16) {
            int s = psrc[rs + j];
            sI[slot * 65 + j] = s;
            float4 a = *(const float4*)(asrc + 4 * (size_t)s);
            float e0 = a.x + ad.x; e0 = e0 > 0.f ? e0 : NEG_SLOPE * e0;
            float e1 = a.y + ad.y; e1 = e1 > 0.f ? e1 : NEG_SLOPE * e1;
            float e2 = a.z + ad.z; e2 = e2 > 0.f ? e2 : NEG_SLOPE * e2;
            float e3 = a.w + ad.w; e3 = e3 > 0.f ? e3 : NEG_SLOPE * e3;
            pL[slot * 65 + j] = make_float4(e0, e1, e2, e3);
            m0 = fmaxf(m0, e0); m1 = fmaxf(m1, e1);
            m2 = fmaxf(m2, e2); m3 = fmaxf(m3, e3);
        }
        #pragma unroll
        for (int off = 1; off < 16; off <<= 1) {
            m0 = fmaxf(m0, __shfl_xor(m0, off));
            m1 = fmaxf(m1, __shfl_xor(m1, off));
            m2 = fmaxf(m2, __shfl_xor(m2, off));
            m3 = fmaxf(m3, __shfl_xor(m3, off));
        }
        for (int j = li; j < deg; j += 16) {
            float4 e = pL[slot * 65 + j];
            float4 p = make_float4(__expf(e.x - m0), __expf(e.y - m1),
                                   __expf(e.z - m2), __expf(e.w - m3));
            pL[slot * 65 + j] = p;
            s0 += p.x; s1 += p.y; s2 += p.z; s3 += p.w;
        }
        #pragma unroll
        for (int off = 1; off < 16; off <<= 1) {
            s0 += __shfl_xor(s0, off);
            s1 += __shfl_xor(s1, off);
            s2 += __shfl_xor(s2, off);
            s3 += __shfl_xor(s3, off);
        }
        // pass 3: simple loop (compiler pipelines); src index from LDS
        #pragma unroll 2
        for (int j = 0; j < deg; ++j) {
            int s = sI[slot * 65 + j];
            float4 p = pL[slot * 65 + j];
            float4 xv = *(const float4*)(x + (size_t)s * 64 + li * 4);
            ACC(p, xv);
        }
    } else {
        // fallback deg > 64: recompute logits, no LDS
        for (int j = li; j < deg; j += 16) {
            int s = psrc[rs + j];
            float4 a = *(const float4*)(asrc + 4 * (size_t)s);
            float e0 = a.x + ad.x; e0 = e0 > 0.f ? e0 : NEG_SLOPE * e0;
            float e1 = a.y + ad.y; e1 = e1 > 0.f ? e1 : NEG_SLOPE * e1;
            float e2 = a.z + ad.z; e2 = e2 > 0.f ? e2 : NEG_SLOPE * e2;
            float e3 = a.w + ad.w; e3 = e3 > 0.f ? e3 : NEG_SLOPE * e3;
            m0 = fmaxf(m0, e0); m1 = fmaxf(m1, e1);
            m2 = fmaxf(m2, e2); m3 = fmaxf(m3, e3);
        }
        #pragma unroll
        for (int off = 1; off < 16; off <<= 1) {
            m0 = fmaxf(m0, __shfl_xor(m0, off));
            m1 = fmaxf(m1, __shfl_xor(m1, off));
            m2 = fmaxf(m2, __shfl_xor(m2, off));
            m3 = fmaxf(m3, __shfl_xor(m3, off));
        }
        for (int j = li; j < deg; j += 16) {
            int s = psrc[rs + j];
            float4 a = *(const float4*)(asrc + 4 * (size_t)s);
            float e0 = a.x + ad.x; e0 = e0 > 0.f ? e0 : NEG_SLOPE * e0;
            float e1 = a.y + ad.y; e1 = e1 > 0.f ? e1 : NEG_SLOPE * e1;
            float e2 = a.z + ad.z; e2 = e2 > 0.f ? e2 : NEG_SLOPE * e2;
            float e3 = a.w + ad.w; e3 = e3 > 0.f ? e3 : NEG_SLOPE * e3;
            s0 += __expf(e0 - m0); s1 += __expf(e1 - m1);
            s2 += __expf(e2 - m2); s3 += __expf(e3 - m3);
        }
        #pragma unroll
        for (int off = 1; off < 16; off <<= 1) {
            s0 += __shfl_xor(s0, off);
            s1 += __shfl_xor(s1, off);
            s2 += __shfl_xor(s2, off);
            s3 += __shfl_xor(s3, off);
        }
        for (int j = 0; j < deg; ++j) {
            int s = psrc[rs + j];
            float4 a = *(const float4*)(asrc + 4 * (size_t)s);
            float e0 = a.x + ad.x; e0 = e0 > 0.f ? e0 : NEG_SLOPE * e0;
            float e1 = a.y + ad.y; e1 = e1 > 0.f ? e1 : NEG_SLOPE * e1;
            float e2 = a.z + ad.z; e2 = e2 > 0.f ? e2 : NEG_SLOPE * e2;
            float e3 = a.w + ad.w; e3 = e3 > 0.f ? e3 : NEG_SLOPE * e3;
            float p0 = __expf(e0 - m0), p1 = __expf(e1 - m1);
            float p2 = __expf(e2 - m2), p3 = __expf(e3 - m3);
            float4 xv = *(const float4*)(x + (size_t)s * 64 + li * 4);
            ACC(make_float4(p0, p1, p2, p3), xv);
        }
    }

    // all pL/sI reads done everywhere, then write zT over the same region
    __syncthreads();
    if (active) {
        float i0 = 0.25f / (s0 + EPS_DEN), i1 = 0.25f / (s1 + EPS_DEN);
        float i2 = 0.25f / (s2 + EPS_DEN), i3 = 0.25f / (s3 + EPS_DEN);
        float* zb = zt + (li * 4) * 18 + slot;
        zb[0]  = a0.x * i0; zb[18] = a0.y * i0; zb[36] = a0.z * i0; zb[54] = a0.w * i0;
        zb += 64 * 18;
        zb[0]  = a1.x * i1; zb[18] = a1.y * i1; zb[36] = a1.z * i1; zb[54] = a1.w * i1;
        zb += 64 * 18;
        zb[0]  = a2.x * i2; zb[18] = a2.y * i2; zb[36] = a2.z * i2; zb[54] = a2.w * i2;
        zb += 64 * 18;
        zb[0]  = a3.x * i3; zb[18] = a3.y * i3; zb[36] = a3.z * i3; zb[54] = a3.w * i3;
    }
    __syncthreads();

    // ---------------- phase 2: out[16x64] = zT^T . W', W from global ----------------
    const int ks = tid >> 6;          // wave id = k subset
    const int ng = (tid >> 4) & 3;    // node group (4 nodes)
    const int og = tid & 15;          // col group (4 cols)
    float acc[4][4];
    #pragma unroll
    for (int i = 0; i < 4; ++i)
        #pragma unroll
        for (int j = 0; j < 4; ++j) acc[i][j] = 0.f;

    const float* wp = W + (size_t)ks * 64 + og * 4;   // W[kk*256 + ks*64 + og*4]
    #pragma unroll 8
    for (int kk = 0; kk < 64; ++kk) {
        int kg = ks * 64 + kk;
        float2 zA = *(const float2*)(zt + kg * 18 + ng * 4);
        float2 zB = *(const float2*)(zt + kg * 18 + ng * 4 + 2);
        float4 wv = *(const float4*)(wp + (size_t)kk * 256);
        float zr[4] = {zA.x, zA.y, zB.x, zB.y};
        float wc4[4] = {wv.x, wv.y, wv.z, wv.w};
        #pragma unroll
        for (int i = 0; i < 4; ++i)
            #pragma unroll
            for (int j = 0; j < 4; ++j)
                acc[i][j] = fmaf(zr[i], wc4[j], acc[i][j]);
    }

    // cross-wave reduction of the 4 k-subsets (red aliases zT)
    __syncthreads();
    #pragma unroll
    for (int i = 0; i < 4; ++i)
        *(float4*)(red + ((ks * 16 + ng * 4 + i) * 16 + og) * 4) =
            make_float4(acc[i][0], acc[i][1], acc[i][2], acc[i][3]);
    __syncthreads();

    {
        int nl = tid >> 4;
        int o  = tid & 15;
        const float4* r4 = (const float4*)red;
        float4 p0 = r4[      nl * 16 + o];
        float4 p1 = r4[256 + nl * 16 + o];
        float4 p2 = r4[512 + nl * 16 + o];
        float4 p3 = r4[768 + nl * 16 + o];
        int gn = blockIdx.x * 16 + nl;
        if (gn < N) {
            float4 b4 = *(const float4*)(bias + o * 4);
            float4 ov;
            ov.x = fmaxf(p0.x + p1.x + p2.x + p3.x + b4.x, 0.f);
            ov.y = fmaxf(p0.y + p1.y + p2.y + p3.y + b4.y, 0.f);
            ov.z = fmaxf(p0.z + p1.z + p2.z + p3.z + b4.z, 0.f);
            ov.w = fmaxf(p0.w + p1.w + p2.w + p3.w + b4.w, 0.f);
            *(float4*)(out + (size_t)gn * 64 + o * 4) = ov;
        }
    }
}

// ---------------- launch ----------------
extern "C" void kernel_launch(void* const* d_in, const int* in_sizes, int n_in,
                              void* d_out, int out_size, void* d_ws, size_t ws_size,
                              hipStream_t stream)
{
    const float* x   = (const float*)d_in[0];
    const int*   ei  = (const int*)d_in[1];
    const float* W1  = (const float*)d_in[4];
    const float* as1 = (const float*)d_in[5];
    const float* ad1 = (const float*)d_in[6];
    const float* b1  = (const float*)d_in[7];
    const float* W2  = (const float*)d_in[8];
    const float* as2 = (const float*)d_in[9];
    const float* ad2 = (const float*)d_in[10];
    const float* b2  = (const float*)d_in[11];

    const int E = in_sizes[1] / 2;
    const int N = N_NODES;

    char* ws = (char*)d_ws;
    size_t off = 0;
    auto alloc = [&](size_t bytes) -> void* {
        void* p = ws + off;
        off = (off + bytes + 255) & ~(size_t)255;
        return p;
    };
    float*        x1    = (float*)alloc((size_t)N * 64 * 4);
    float*        asrc  = (float*)alloc((size_t)N * 4 * 4);
    float*        adst  = (float*)alloc((size_t)N * 4 * 4);
    float*        WaSD  = (float*)alloc(64 * 8 * 4);
    int*          row   = (int*)alloc((size_t)(N + 1) * 4);
    int*          psrc  = (int*)alloc((size_t)E * 4);
    int*          bh    = (int*)alloc((size_t)NBUCK * NBLK * 4);
    int*          boffL = (int*)alloc((size_t)NBUCK * NBLK * 4);
    int*          btot  = (int*)alloc((NBUCK + 1) * 4);
    int*          bbase = (int*)alloc((NBUCK + 1) * 4);
    unsigned int* stage = (unsigned int*)alloc((size_t)E * 4);

    // CSR (shared by both layers)
    hist_bucket_k<<<NBLK, 256, 0, stream>>>(ei, bh, E);
    bscan_k<<<NBUCK, 64, 0, stream>>>(bh, boffL, btot);
    btot_k<<<1, 256, 0, stream>>>(btot, bbase, row, N, E);
    bplace_k<<<NBLK, 256, 0, stream>>>(ei, bbase, boffL, stage, E);
    bscatter_k<<<NBUCK, 256, 0, stream>>>(stage, bbase, row, psrc, N);

    const int nblk64 = (N + 63) / 64;
    const int nblk16 = (N + 15) / 16;

    // layer 1
    prep_k<<<1, 256, 0, stream>>>(W1, as1, ad1, WaSD);
    alpha_k<<<nblk64, 256, 0, stream>>>(x, WaSD, asrc, adst, N);
    aggzw_k<<<nblk16, 256, 0, stream>>>(x, asrc, adst, row, psrc, W1, b1, x1, N);

    // layer 2
    prep_k<<<1, 256, 0, stream>>>(W2, as2, ad2, WaSD);
    alpha_k<<<nblk64, 256, 0, stream>>>(x1, WaSD, asrc, adst, N);
    aggzw_k<<<nblk16, 256, 0, stream>>>(x1, asrc, adst, row, psrc, W2, b2, (float*)d_out, N);
}